// Round 10
// baseline (226.200 us; speedup 1.0000x reference)
//
#include <hip/hip_runtime.h>
#include <hip/hip_bf16.h>

// Problem: B,W,H,L = 2,32,32,32 -> N=65536 voxels; D=512, E=64 heads, V=16.
// fp32 tensors; out fp32. Fused kernel: grid = 64 heads x 16 slices.
// Round-9: infra outage confirmed by round-8 control (byte-identical
// round-4 source, previously 82 us, also "container failed twice").
// Resubmitting the experiment: round-4 structure + ONE change — depth-4
// k-step prefetch rotation in the decode loop (8 outstanding 16B x-loads
// per wave, issued ahead in program order) to attack exposed HBM latency
// (R4 counters: HBM 15%, VALUBusy 3.2%, MfmaUtil 0.5% — all pipes idle).
#define DDIM 512
#define VDIM 16
#define EHEADS 64
#define NVOX 65536
#define QPERH 16
#define SLICE (NVOX / QPERH)          // 4096 voxels per slice
#define NBLOCKS (EHEADS * QPERH)      // 1024 blocks (4/CU)
#define CAPL 2048
#define KSTEPS (DDIM / 32)            // 16 MFMA K-steps
#define PFD 4                         // prefetch depth (k-steps)

typedef __bf16  bf16x8  __attribute__((ext_vector_type(8)));
typedef float   floatx4 __attribute__((ext_vector_type(4)));

__global__ __launch_bounds__(256) void fused_decode_kernel(
    const int*   __restrict__ btg,   // (NVOX,)
    const int*   __restrict__ b2h,   // (256,)
    const float* __restrict__ x,     // (NVOX, D)
    const float* __restrict__ Wh,    // (E, V, D)
    const float* __restrict__ bh,    // (E, V)
    float*       __restrict__ out)   // (NVOX, V)
{
    __shared__ int    lut[256];
    __shared__ int    list[CAPL];                 // 8 KB
    __shared__ bf16x8 Wfrag[KSTEPS * 64];         // 16 KB, MFMA fragment order
    __shared__ int    cursor;

    const int tid  = threadIdx.x;
    const int lane = tid & 63;
    const int wv   = tid >> 6;                    // wave in block (0..3)
    const int e    = blockIdx.x >> 4;             // head
    const int q    = blockIdx.x & (QPERH - 1);    // slice
    const int m    = lane & 15;
    const int quad = lane >> 4;

    lut[tid] = b2h[tid];                          // blockDim == 256 types
    if (tid == 0) cursor = 0;
    __syncthreads();

    // ---- Stage W[e] -> LDS in fragment order (bf16), once per block -------
    // Wfrag[k0*64 + ln] = W[e][ln&15][k0*32 + (ln>>4)*8 + j], j=0..7
#pragma unroll
    for (int i = 0; i < 4; ++i) {
        const int f  = i * 256 + tid;             // fragment id 0..1023
        const int k0 = f >> 6;
        const int ln = f & 63;
        const float* src = Wh + ((size_t)e * VDIM + (ln & 15)) * DDIM
                              + k0 * 32 + (ln >> 4) * 8;
        const floatx4 b0 = *(const floatx4*)src;
        const floatx4 b1 = *(const floatx4*)(src + 4);
        bf16x8 bf;
#pragma unroll
        for (int j = 0; j < 4; ++j) {
            bf[j] = (__bf16)b0[j]; bf[4 + j] = (__bf16)b1[j];
        }
        Wfrag[f] = bf;                            // ds_write_b128, lane-seq
    }

    // ---- Ballot-compact matching voxel indices into LDS --------------------
    const int base = q * SLICE;
#pragma unroll 4
    for (int it = 0; it < SLICE / 256; ++it) {
        const int n = base + it * 256 + tid;      // coalesced btg read
        const bool match = (lut[btg[n]] == e);
        const unsigned long long mask = __ballot(match);
        int wb = 0;
        if (lane == 0) wb = atomicAdd(&cursor, __popcll(mask));
        wb = __shfl(wb, 0);
        if (match) {
            const int p = wb + __popcll(mask & ((1ull << lane) - 1ull));
            if (p < CAPL) list[p] = n;            // cap: needs K_h>128 to hit
        }
    }
    __syncthreads();                              // guards list AND Wfrag

    int cnt = cursor;
    if (cnt > CAPL) cnt = CAPL;
    const int ntiles = (cnt + 15) >> 4;
    const float bv = bh[e * VDIM + m];

    // ---- Decode: one wave per tile; depth-PFD rotating prefetch ------------
    for (int t = wv; t < ntiles; t += 4) {
        const int rs = t * 16;
        int rm = rs + m;
        if (rm >= cnt) rm = cnt - 1;              // clamp tail (stores guarded)
        const int idx_m = list[rm];               // LDS, quad-broadcast
        const float* __restrict__ xr = x + (size_t)idx_m * DDIM + quad * 8;

        floatx4 p0[PFD], p1[PFD];
#pragma unroll
        for (int i = 0; i < PFD; ++i) {           // 8 loads in flight
            p0[i] = *(const floatx4*)(xr + i * 32);
            p1[i] = *(const floatx4*)(xr + i * 32 + 4);
        }

        floatx4 acc = {0.f, 0.f, 0.f, 0.f};
#pragma unroll
        for (int k0 = 0; k0 < KSTEPS; ++k0) {
            const floatx4 a0 = p0[k0 & (PFD - 1)];
            const floatx4 a1 = p1[k0 & (PFD - 1)];
            if (k0 + PFD < KSTEPS) {              // compile-time condition
                p0[k0 & (PFD - 1)] = *(const floatx4*)(xr + (k0 + PFD) * 32);
                p1[k0 & (PFD - 1)] = *(const floatx4*)(xr + (k0 + PFD) * 32 + 4);
            }
            bf16x8 af;
#pragma unroll
            for (int j = 0; j < 4; ++j) {
                af[j] = (__bf16)a0[j]; af[4 + j] = (__bf16)a1[j];
            }
            acc = __builtin_amdgcn_mfma_f32_16x16x32_bf16(
                      af, Wfrag[k0 * 64 + lane], acc, 0, 0, 0);
        }

        // D: col = m (output v), row = quad*4 + r (voxel within tile)
#pragma unroll
        for (int r = 0; r < 4; ++r) {
            const int o = rs + quad * 4 + r;
            if (o < cnt)
                out[(size_t)list[o] * VDIM + m] = acc[r] + bv;
        }
    }
}

extern "C" void kernel_launch(void* const* d_in, const int* in_sizes, int n_in,
                              void* d_out, int out_size, void* d_ws, size_t ws_size,
                              hipStream_t stream)
{
    const int*   btg = (const int*)d_in[0];
    const float* x   = (const float*)d_in[1];
    const float* Wh  = (const float*)d_in[2];
    const float* bh  = (const float*)d_in[3];
    const int*   b2h = (const int*)d_in[4];
    float*       out = (float*)d_out;
    (void)d_ws; (void)ws_size; (void)in_sizes; (void)n_in; (void)out_size;

    fused_decode_kernel<<<NBLOCKS, 256, 0, stream>>>(btg, b2h, x, Wh, bh, out);
}

// Round 11
// 225.073 us; speedup vs baseline: 1.0050x; 1.0050x over previous
//
#include <hip/hip_runtime.h>
#include <hip/hip_bf16.h>

// Problem: B,W,H,L = 2,32,32,32 -> N=65536 voxels; D=512, E=64 heads, V=16.
// fp32 tensors; out fp32. Round-11: R10 showed the register allocator cancels
// VGPR-destined prefetch (VGPR stayed 64, counters identical to R4). Switch
// to global_load_lds DMA staging (no dest VGPRs -> in-flight depth is
// explicit in vmcnt, uncancelable). Also: atomic-free per-wave scan, 512
// blocks (2/CU, all resident, one round).
#define DDIM 512
#define VDIM 16
#define EHEADS 64
#define NVOX 65536
#define QPERH 8
#define SLICE (NVOX / QPERH)          // 8192 voxels per block slice
#define NBLOCKS (EHEADS * QPERH)      // 512 blocks = 2/CU, all resident
#define WRANGE (SLICE / 4)            // 2048 voxels per wave
#define WCAP 512                      // per-wave list cap (mean ~32, 43 sigma)
#define KSTEPS 16                     // K=32 MFMA steps
#define GSTEPS 4                      // k-steps per staging round (8 KB)
#define NG (KSTEPS / GSTEPS)          // 4 staging rounds per tile

typedef __bf16  bf16x8  __attribute__((ext_vector_type(8)));
typedef float   floatx4 __attribute__((ext_vector_type(4)));
typedef __attribute__((address_space(3))) unsigned int* lds_u32p;
typedef const __attribute__((address_space(1))) unsigned int* gbl_u32p;

__global__ __launch_bounds__(256) void fused_decode_kernel(
    const int*   __restrict__ btg,   // (NVOX,)
    const int*   __restrict__ b2h,   // (256,)
    const float* __restrict__ x,     // (NVOX, D)
    const float* __restrict__ Wh,    // (E, V, D)
    const float* __restrict__ bh,    // (E, V)
    float*       __restrict__ out)   // (NVOX, V)
{
    __shared__ int    lut[256];                   // 1 KB
    __shared__ bf16x8 Wfrag[KSTEPS * 64];         // 16 KB, MFMA fragment order
    __shared__ int    wlist[4][WCAP];             // 8 KB, per-wave lists
    __shared__ __align__(16) char stage[4][GSTEPS * 16 * 128]; // 4 x 8 KB

    const int tid  = threadIdx.x;
    const int lane = tid & 63;
    const int wv   = tid >> 6;                    // wave in block (0..3)
    const int e    = blockIdx.x >> 3;             // head
    const int q    = blockIdx.x & (QPERH - 1);    // slice
    const int m    = lane & 15;
    const int quad = lane >> 4;

    lut[tid] = b2h[tid];

    // ---- Stage W[e] -> LDS in fragment order (bf16), once per block -------
    // Wfrag[k0*64 + ln] = W[e][ln&15][k0*32 + (ln>>4)*8 + j], j=0..7
#pragma unroll
    for (int i = 0; i < 4; ++i) {
        const int f  = i * 256 + tid;
        const int k0 = f >> 6, ln = f & 63;
        const float* src = Wh + ((size_t)e * VDIM + (ln & 15)) * DDIM
                              + k0 * 32 + (ln >> 4) * 8;
        const floatx4 b0 = *(const floatx4*)src;
        const floatx4 b1 = *(const floatx4*)(src + 4);
        bf16x8 bf;
#pragma unroll
        for (int j = 0; j < 4; ++j) {
            bf[j] = (__bf16)b0[j]; bf[4 + j] = (__bf16)b1[j];
        }
        Wfrag[f] = bf;
    }
    __syncthreads();                              // ONLY barrier in the kernel

    // ---- Per-wave atomic-free scan: register cursor + ballot prefix --------
    const int wbase = q * SLICE + wv * WRANGE;
    int cnt = 0;
#pragma unroll 4
    for (int i = 0; i < WRANGE / 64; ++i) {       // 32 iterations
        const int n = wbase + i * 64 + lane;      // wave-contiguous btg read
        const bool match = (lut[btg[n]] == e);
        const unsigned long long mk = __ballot(match);
        if (match) {
            const int p = cnt + __popcll(mk & ((1ull << lane) - 1ull));
            if (p < WCAP) wlist[wv][p] = n;
        }
        cnt += __popcll(mk);
    }
    if (cnt > WCAP) cnt = WCAP;

    const float bv = bh[e * VDIM + m];
    char* const stw = stage[wv];                  // per-wave staging buffer
    const int ntiles = (cnt + 15) >> 4;

    // ---- Decode: per tile, NG staging rounds of GSTEPS k-steps -------------
    // LDS layout per round: flat slot f in [0,512): row r=f>>5, 16B-col c=f&31
    // holding global 16B-col c ^ (r&7)  (XOR swizzle -> conflict-free reads).
    for (int t = 0; t < ntiles; ++t) {
        const int rs = t * 16;
        int rm = rs + m;
        if (rm >= cnt) rm = cnt - 1;              // clamp tail (stores guarded)
        const int idx_m = wlist[wv][rm];          // lane L holds row L&15

        floatx4 acc = {0.f, 0.f, 0.f, 0.f};
#pragma unroll
        for (int g = 0; g < NG; ++g) {
            // Issue 8 DMA loads: instr j covers rows j*2+(lane>>5), 512B each
#pragma unroll
            for (int j = 0; j < 8; ++j) {
                const int r  = j * 2 + (lane >> 5);
                const int ir = __shfl(idx_m, r);  // voxel id for row r
                const int cs = (lane & 31) ^ (r & 7);
                const char* gp = (const char*)x
                               + (size_t)ir * (DDIM * 4) + g * 512 + cs * 16;
                __builtin_amdgcn_global_load_lds(
                    (gbl_u32p)gp, (lds_u32p)(stw + j * 1024), 16, 0, 0);
            }
            asm volatile("" ::: "memory");
            __builtin_amdgcn_s_waitcnt(0x0F70);   // vmcnt(0) only
            asm volatile("" ::: "memory");

#pragma unroll
            for (int k = 0; k < GSTEPS; ++k) {
                const int cb = k * 8 + quad * 2;  // global 16B-col in window
                const floatx4 a0 = *(const floatx4*)
                    (stw + m * 512 + (((cb)     ^ (m & 7)) << 4));
                const floatx4 a1 = *(const floatx4*)
                    (stw + m * 512 + (((cb + 1) ^ (m & 7)) << 4));
                bf16x8 af;
#pragma unroll
                for (int j = 0; j < 4; ++j) {
                    af[j] = (__bf16)a0[j]; af[4 + j] = (__bf16)a1[j];
                }
                acc = __builtin_amdgcn_mfma_f32_16x16x32_bf16(
                          af, Wfrag[(g * GSTEPS + k) * 64 + lane], acc, 0, 0, 0);
            }
        }

        // D: col = m (output v), row = quad*4 + r (voxel within tile)
#pragma unroll
        for (int r = 0; r < 4; ++r) {
            const int o = rs + quad * 4 + r;
            if (o < cnt)
                out[(size_t)wlist[wv][o] * VDIM + m] = acc[r] + bv;
        }
    }
}

extern "C" void kernel_launch(void* const* d_in, const int* in_sizes, int n_in,
                              void* d_out, int out_size, void* d_ws, size_t ws_size,
                              hipStream_t stream)
{
    const int*   btg = (const int*)d_in[0];
    const float* x   = (const float*)d_in[1];
    const float* Wh  = (const float*)d_in[2];
    const float* bh  = (const float*)d_in[3];
    const int*   b2h = (const int*)d_in[4];
    float*       out = (float*)d_out;
    (void)d_ws; (void)ws_size; (void)in_sizes; (void)n_in; (void)out_size;

    fused_decode_kernel<<<NBLOCKS, 256, 0, stream>>>(btg, b2h, x, Wh, bh, out);
}